// Round 1
// baseline (769.769 us; speedup 1.0000x reference)
//
#include <hip/hip_runtime.h>

#define NSH   100
#define NPRIM 8
#define NAOC  280
#define NAOS  260
#define NATOM 20
#define MT    64      // points per block
#define KC    40      // c2s K-chunk rows (280 = 7*40)
#define CPAD  264     // c2s chunk padded columns (260 -> 264, zero fill)
#define RSQRT3 0.57735026918962576f

__global__ __launch_bounds__(256) void gto_fused(
    const float* __restrict__ coords,
    const float* __restrict__ centers,
    const float* __restrict__ zetas,
    const float* __restrict__ coeffs,
    const float* __restrict__ norm,
    const float* __restrict__ c2s,
    float* __restrict__ out,
    int n)
{
    __shared__ float sAos[NAOC * MT];      // [k][p] transposed AO tile, 71680 B
    __shared__ float sB[KC * CPAD];        // c2s chunk, 42240 B
    __shared__ float sZeta[NSH * NPRIM];
    __shared__ float sCoef[NSH * NPRIM];
    __shared__ float sCen[NATOM * 3];
    __shared__ float sNorm[NAOC];          // normalization * anorm folded
    __shared__ float sCx[MT], sCy[MT], sCz[MT];

    const int t  = threadIdx.x;
    const int P0 = blockIdx.x * MT;

    // ---- stage small constant data ----
    for (int i = t; i < NSH * NPRIM; i += 256) { sZeta[i] = zetas[i]; sCoef[i] = coeffs[i]; }
    for (int i = t; i < NATOM * 3; i += 256) sCen[i] = centers[i];
    for (int i = t; i < NAOC; i += 256) {
        float nv = norm[i];
        if (i >= 160) {
            int c = (i - 160) % 6;
            if (c == 0 || c == 3 || c == 5) nv *= RSQRT3;   // anorm for xx,yy,zz
        }
        sNorm[i] = nv;
    }
    // coords for this block's 64 points
    for (int i = t; i < MT * 3; i += 256) {
        int gi = P0 * 3 + i;
        float v = (gi < 3 * n) ? coords[gi] : 0.0f;
        int p = i / 3, c = i - 3 * (i / 3);
        if (c == 0) sCx[p] = v; else if (c == 1) sCy[p] = v; else sCz[p] = v;
    }
    __syncthreads();

    // ---- phase 1: AO tile [280][64] ----
    // task id = shell*64 + point; shell is wave-uniform (64 consecutive ids per wave)
    #pragma unroll 1
    for (int it = 0; it < (NSH * MT) / 256; ++it) {
        int id = it * 256 + t;
        int s = id >> 6, p = id & 63;
        int a = s / 5, rr = s - a * 5;
        float dx = sCx[p] - sCen[a * 3 + 0];
        float dy = sCy[p] - sCen[a * 3 + 1];
        float dz = sCz[p] - sCen[a * 3 + 2];
        float r2 = dx * dx + dy * dy + dz * dz;
        float rad = 0.0f;
        #pragma unroll
        for (int pr = 0; pr < NPRIM; ++pr)
            rad += sCoef[s * NPRIM + pr] * __expf(-sZeta[s * NPRIM + pr] * r2);
        if (rr < 2) {              // s shell
            int ao = 2 * a + rr;
            sAos[ao * MT + p] = rad * sNorm[ao];
        } else if (rr < 4) {       // p shell: x, y, z
            int base = 40 + (2 * a + (rr - 2)) * 3;
            sAos[(base + 0) * MT + p] = dx * rad * sNorm[base + 0];
            sAos[(base + 1) * MT + p] = dy * rad * sNorm[base + 1];
            sAos[(base + 2) * MT + p] = dz * rad * sNorm[base + 2];
        } else {                   // d shell: xx,xy,xz,yy,yz,zz
            int base = 160 + 6 * a;
            sAos[(base + 0) * MT + p] = dx * dx * rad * sNorm[base + 0];
            sAos[(base + 1) * MT + p] = dx * dy * rad * sNorm[base + 1];
            sAos[(base + 2) * MT + p] = dx * dz * rad * sNorm[base + 2];
            sAos[(base + 3) * MT + p] = dy * dy * rad * sNorm[base + 3];
            sAos[(base + 4) * MT + p] = dy * dz * rad * sNorm[base + 4];
            sAos[(base + 5) * MT + p] = dz * dz * rad * sNorm[base + 5];
        }
    }
    __syncthreads();

    // ---- phase 2: [64,280] x [280,260] register-blocked GEMM ----
    const int rg = t & 7;    // row group: rows rg*8 .. rg*8+7
    const int cg = t >> 3;   // col group: cols cg*8 .. cg*8+7 (+ predicated 9th)
    float acc[8][8];
    float acc9[8];
    #pragma unroll
    for (int r = 0; r < 8; ++r) {
        acc9[r] = 0.0f;
        #pragma unroll
        for (int u = 0; u < 8; ++u) acc[r][u] = 0.0f;
    }

    for (int kc = 0; kc < NAOC; kc += KC) {
        // stage B chunk (zero-pad cols 260..263)
        for (int i = t; i < KC * CPAD; i += 256) {
            int row = i / CPAD, col = i - row * CPAD;
            sB[i] = (col < NAOS) ? c2s[(kc + row) * NAOS + col] : 0.0f;
        }
        __syncthreads();
        #pragma unroll 1
        for (int kk = 0; kk < KC; ++kk) {
            const float4 a0 = *(const float4*)&sAos[(kc + kk) * MT + rg * 8];
            const float4 a1 = *(const float4*)&sAos[(kc + kk) * MT + rg * 8 + 4];
            const float4 b0 = *(const float4*)&sB[kk * CPAD + cg * 8];
            const float4 b1 = *(const float4*)&sB[kk * CPAD + cg * 8 + 4];
            const float b9 = sB[kk * CPAD + 256 + (cg & 7)];
            float av[8] = {a0.x, a0.y, a0.z, a0.w, a1.x, a1.y, a1.z, a1.w};
            float bv[8] = {b0.x, b0.y, b0.z, b0.w, b1.x, b1.y, b1.z, b1.w};
            #pragma unroll
            for (int r = 0; r < 8; ++r) {
                #pragma unroll
                for (int u = 0; u < 8; ++u) acc[r][u] += av[r] * bv[u];
                acc9[r] += av[r] * b9;
            }
        }
        __syncthreads();
    }

    // ---- write out ----
    #pragma unroll
    for (int r = 0; r < 8; ++r) {
        int P = P0 + rg * 8 + r;
        if (P < n) {
            float4* o = (float4*)&out[(size_t)P * NAOS + cg * 8];
            o[0] = make_float4(acc[r][0], acc[r][1], acc[r][2], acc[r][3]);
            o[1] = make_float4(acc[r][4], acc[r][5], acc[r][6], acc[r][7]);
            if (cg < 4) out[(size_t)P * NAOS + 256 + cg] = acc9[r];
        }
    }
}

extern "C" void kernel_launch(void* const* d_in, const int* in_sizes, int n_in,
                              void* d_out, int out_size, void* d_ws, size_t ws_size,
                              hipStream_t stream) {
    const float* coords  = (const float*)d_in[0];
    const float* centers = (const float*)d_in[1];
    const float* zetas   = (const float*)d_in[2];
    const float* coeffs  = (const float*)d_in[3];
    const float* norm    = (const float*)d_in[4];
    const float* c2s     = (const float*)d_in[5];
    float* out = (float*)d_out;
    int n = in_sizes[0] / 3;
    int grid = (n + MT - 1) / MT;
    gto_fused<<<grid, 256, 0, stream>>>(coords, centers, zetas, coeffs, norm, c2s, out, n);
}

// Round 2
// 170.875 us; speedup vs baseline: 4.5049x; 4.5049x over previous
//
#include <hip/hip_runtime.h>

typedef unsigned int uint;
typedef unsigned short ushort;
typedef __attribute__((ext_vector_type(8))) short short8;   // 8 bf16 (4 VGPRs)
typedef __attribute__((ext_vector_type(4))) float f32x4;
typedef __attribute__((ext_vector_type(4))) uint uint4v;

#define NSH   100
#define NPRIM 8
#define NAOC  280
#define NAOS  260
#define NATOM 20
#define KP    288          // K padded to 9*32
#define NKB   9
#define MT    64           // points per block
#define NCOLP 272          // N padded to 17*16
#define BCH   (32 * NCOLP) // 8704 elems per B chunk
#define ARS   40           // A-frag row stride (ushorts): 32 data + 8 pad (bank spread)
#define RSQRT3 0.57735026918962576f

__device__ __forceinline__ ushort bf16_rne(float x) {
    uint u = __float_as_uint(x);
    return (ushort)((u + 0x7FFFu + ((u >> 16) & 1u)) >> 16);
}
__device__ __forceinline__ float bf16_to_f(ushort h) {
    return __uint_as_float(((uint)h) << 16);
}

// ---- prep: split cart2sph into bf16 hi/lo in MFMA B-fragment order ----
__global__ void prep_b(const float* __restrict__ c2s, ushort* __restrict__ wsHi,
                       ushort* __restrict__ wsLo) {
    int id = blockIdx.x * 256 + threadIdx.x;
    if (id >= KP * NCOLP) return;
    int k = id / NCOLP, col = id % NCOLP;
    float v = (k < NAOC && col < NAOS) ? c2s[k * NAOS + col] : 0.0f;
    ushort hi = bf16_rne(v);
    ushort lo = bf16_rne(v - bf16_to_f(hi));
    int off = (k >> 5) * BCH +
              (((col >> 4) * 4 + ((k & 31) >> 3)) * 16 + (col & 15)) * 8 + (k & 7);
    wsHi[off] = hi;
    wsLo[off] = lo;
}

template <bool USEWS>
__global__ __launch_bounds__(256, 2) void gto_mfma(
    const float* __restrict__ coords, const float* __restrict__ centers,
    const float* __restrict__ zetas, const float* __restrict__ coeffs,
    const float* __restrict__ norm, const float* __restrict__ c2s,
    const ushort* __restrict__ wsHi, const ushort* __restrict__ wsLo,
    float* __restrict__ out, int n)
{
    __shared__ float  sRad[NSH * MT];                 // 25600 B
    __shared__ ushort sBhi[BCH], sBlo[BCH];           // 34816 B
    __shared__ ushort sAhi[MT * ARS], sAlo[MT * ARS]; // 10240 B
    __shared__ float  sZeta[NSH * NPRIM], sCoef[NSH * NPRIM]; // 6400 B
    __shared__ float  sCen[NATOM * 3];
    __shared__ float  sCx[MT], sCy[MT], sCz[MT];
    __shared__ float  sNormF[KP];
    __shared__ int    sMeta[KP];

    const int t  = threadIdx.x;
    const int P0 = blockIdx.x * MT;

    // ---- stage constants + per-AO metadata ----
    for (int i = t; i < NSH * NPRIM; i += 256) { sZeta[i] = zetas[i]; sCoef[i] = coeffs[i]; }
    for (int i = t; i < NATOM * 3; i += 256) sCen[i] = centers[i];
    for (int i = t; i < MT * 3; i += 256) {
        int gi = P0 * 3 + i;
        float v = (gi < 3 * n) ? coords[gi] : 0.0f;
        int p = i / 3, c = i - 3 * (i / 3);
        if (c == 0) sCx[p] = v; else if (c == 1) sCy[p] = v; else sCz[p] = v;
    }
    for (int k = t; k < KP; k += 256) {
        int shell = 0, atom = 0, s1 = 0, s2 = 0; float nf = 0.0f;
        if (k < 40) {
            atom = k >> 1; shell = 5 * atom + (k & 1); nf = norm[k];
        } else if (k < 160) {
            int i = k - 40; int ip = i / 3; int c = i - 3 * ip;
            atom = ip >> 1; shell = 5 * atom + 2 + (ip & 1); s1 = 1 + c; nf = norm[k];
        } else if (k < NAOC) {
            int i = k - 160; atom = i / 6; shell = 5 * atom + 4; int c = i - 6 * atom;
            if      (c == 0) { s1 = 1; s2 = 1; }
            else if (c == 1) { s1 = 1; s2 = 2; }
            else if (c == 2) { s1 = 1; s2 = 3; }
            else if (c == 3) { s1 = 2; s2 = 2; }
            else if (c == 4) { s1 = 2; s2 = 3; }
            else             { s1 = 3; s2 = 3; }
            nf = norm[k];
            if (c == 0 || c == 3 || c == 5) nf *= RSQRT3;
        }
        sMeta[k]  = shell | (atom << 7) | (s1 << 12) | (s2 << 14);
        sNormF[k] = nf;
    }
    __syncthreads();

    // ---- radial table: rad[shell][point] ----
    #pragma unroll 1
    for (int it = 0; it < (NSH * MT) / 256; ++it) {
        int id = it * 256 + t;
        int s = id >> 6, p = id & 63;
        int a = s / 5;
        float dx = sCx[p] - sCen[3 * a];
        float dy = sCy[p] - sCen[3 * a + 1];
        float dz = sCz[p] - sCen[3 * a + 2];
        float r2 = dx * dx + dy * dy + dz * dz;
        float rad = 0.0f;
        #pragma unroll
        for (int pr = 0; pr < NPRIM; ++pr)
            rad += sCoef[s * NPRIM + pr] * __expf(-sZeta[s * NPRIM + pr] * r2);
        sRad[s * MT + p] = rad;
    }
    __syncthreads();

    const int lane = t & 63, w = t >> 6;
    const int lr = lane & 15, lg = lane >> 4;

    f32x4 acc[5][4];
    #pragma unroll
    for (int i = 0; i < 5; ++i)
        #pragma unroll
        for (int m = 0; m < 4; ++m)
            acc[i][m] = (f32x4){0.0f, 0.0f, 0.0f, 0.0f};

    for (int kb = 0; kb < NKB; ++kb) {
        // ---- stage B chunk (frag order, hi/lo) ----
        if (USEWS) {
            const uint4v* srcH = (const uint4v*)(wsHi + kb * BCH);
            const uint4v* srcL = (const uint4v*)(wsLo + kb * BCH);
            uint4v* dstH = (uint4v*)sBhi;
            uint4v* dstL = (uint4v*)sBlo;
            for (int i = t; i < BCH / 8; i += 256) { dstH[i] = srcH[i]; dstL[i] = srcL[i]; }
        } else {
            for (int i = t; i < BCH; i += 256) {
                int col = i % NCOLP, kl = i / NCOLP;
                int k = kb * 32 + kl;
                float v = (k < NAOC && col < NAOS) ? c2s[k * NAOS + col] : 0.0f;
                ushort hi = bf16_rne(v);
                ushort lo = bf16_rne(v - bf16_to_f(hi));
                int off = (((col >> 4) * 4 + (kl >> 3)) * 16 + (col & 15)) * 8 + (kl & 7);
                sBhi[off] = hi;
                sBlo[off] = lo;
            }
        }
        // ---- stage A frags: [p][kl] bf16 hi/lo, row stride ARS ----
        #pragma unroll 1
        for (int it = 0; it < 4; ++it) {
            int id = it * 256 + t;          // 64p x 16 klp
            int p = id & 63, klp = id >> 6;
            uint hpack = 0, lpack = 0;
            #pragma unroll
            for (int h = 0; h < 2; ++h) {
                int kl = klp * 2 + h;
                int k = kb * 32 + kl;
                int meta = sMeta[k];
                int s = meta & 127, a = (meta >> 7) & 31;
                int s1 = (meta >> 12) & 3, s2 = (meta >> 14) & 3;
                float dx = sCx[p] - sCen[3 * a];
                float dy = sCy[p] - sCen[3 * a + 1];
                float dz = sCz[p] - sCen[3 * a + 2];
                float m1 = (s1 == 0) ? 1.0f : ((s1 == 1) ? dx : ((s1 == 2) ? dy : dz));
                float m2 = (s2 == 0) ? 1.0f : ((s2 == 1) ? dx : ((s2 == 2) ? dy : dz));
                float v = sRad[s * MT + p] * m1 * m2 * sNormF[k];
                ushort hi = bf16_rne(v);
                ushort lo = bf16_rne(v - bf16_to_f(hi));
                hpack |= ((uint)hi) << (16 * h);
                lpack |= ((uint)lo) << (16 * h);
            }
            ((uint*)sAhi)[p * (ARS / 2) + klp] = hpack;
            ((uint*)sAlo)[p * (ARS / 2) + klp] = lpack;
        }
        __syncthreads();

        // ---- MFMA: wave w -> all 4 M-tiles x its N-tiles ----
        short8 ahi[4], alo[4];
        #pragma unroll
        for (int m = 0; m < 4; ++m) {
            int rowp = m * 16 + lr;
            ahi[m] = *(const short8*)(sAhi + rowp * ARS + lg * 8);
            alo[m] = *(const short8*)(sAlo + rowp * ARS + lg * 8);
        }
        #pragma unroll
        for (int i = 0; i < 5; ++i) {
            if (i < 4 || w == 0) {
                int nt = (i == 4) ? 16 : (w * 4 + i);
                const short8 bhi = *(const short8*)(sBhi + (nt * 64 + lg * 16 + lr) * 8);
                const short8 blo = *(const short8*)(sBlo + (nt * 64 + lg * 16 + lr) * 8);
                #pragma unroll
                for (int m = 0; m < 4; ++m)
                    acc[i][m] = __builtin_amdgcn_mfma_f32_16x16x32_bf16(ahi[m], bhi, acc[i][m], 0, 0, 0);
                #pragma unroll
                for (int m = 0; m < 4; ++m)
                    acc[i][m] = __builtin_amdgcn_mfma_f32_16x16x32_bf16(ahi[m], blo, acc[i][m], 0, 0, 0);
                #pragma unroll
                for (int m = 0; m < 4; ++m)
                    acc[i][m] = __builtin_amdgcn_mfma_f32_16x16x32_bf16(alo[m], bhi, acc[i][m], 0, 0, 0);
            }
        }
        __syncthreads();
    }

    // ---- epilogue: D[m][n]: col = nt*16 + (lane&15), row = mt*16 + (lane>>4)*4 + r ----
    #pragma unroll
    for (int i = 0; i < 5; ++i) {
        if (i < 4 || w == 0) {
            int nt = (i == 4) ? 16 : (w * 4 + i);
            int col = nt * 16 + lr;
            if (col < NAOS) {
                #pragma unroll
                for (int m = 0; m < 4; ++m) {
                    #pragma unroll
                    for (int r = 0; r < 4; ++r) {
                        int P = P0 + m * 16 + lg * 4 + r;
                        if (P < n) out[(size_t)P * NAOS + col] = acc[i][m][r];
                    }
                }
            }
        }
    }
}

extern "C" void kernel_launch(void* const* d_in, const int* in_sizes, int n_in,
                              void* d_out, int out_size, void* d_ws, size_t ws_size,
                              hipStream_t stream) {
    const float* coords  = (const float*)d_in[0];
    const float* centers = (const float*)d_in[1];
    const float* zetas   = (const float*)d_in[2];
    const float* coeffs  = (const float*)d_in[3];
    const float* norm    = (const float*)d_in[4];
    const float* c2s     = (const float*)d_in[5];
    float* out = (float*)d_out;
    int n = in_sizes[0] / 3;
    int grid = (n + MT - 1) / MT;

    const size_t WS_NEED = (size_t)2 * KP * NCOLP * sizeof(ushort);  // 313344 B
    ushort* wsHi = (ushort*)d_ws;
    ushort* wsLo = wsHi + (size_t)KP * NCOLP;

    if (ws_size >= WS_NEED) {
        prep_b<<<(KP * NCOLP + 255) / 256, 256, 0, stream>>>(c2s, wsHi, wsLo);
        gto_mfma<true><<<grid, 256, 0, stream>>>(coords, centers, zetas, coeffs,
                                                 norm, c2s, wsHi, wsLo, out, n);
    } else {
        gto_mfma<false><<<grid, 256, 0, stream>>>(coords, centers, zetas, coeffs,
                                                  norm, c2s, nullptr, nullptr, out, n);
    }
}

// Round 3
// 151.510 us; speedup vs baseline: 5.0806x; 1.1278x over previous
//
#include <hip/hip_runtime.h>

typedef unsigned int uint;
typedef unsigned short ushort;
typedef __attribute__((ext_vector_type(8))) short short8;   // 8 bf16
typedef __attribute__((ext_vector_type(4))) float f32x4;
typedef __attribute__((ext_vector_type(4))) uint uint4v;

#define NSH   100
#define NPRIM 8
#define NAOC  280
#define NAOS  260
#define NATOM 20
#define KP    288
#define NKB   9
#define MT    64
#define NCOLP 272
#define BCH   (32 * NCOLP)   // ushorts per half-chunk (8704)
#define RSQRT3 0.57735026918962576f

// LDS pool byte offsets
#define O_RAD   0        // 100*64*4 = 25600
#define O_BHI   25600    // 17408
#define O_BLO   43008    // 17408
#define O_AHI   60416    // 4096
#define O_ALO   64512    // 4096
#define O_ZETA  68608    // 3200
#define O_COEF  71808    // 3200
#define O_CEN   75008    // 240
#define O_CX    75264    // 256
#define O_CY    75520    // 256
#define O_CZ    75776    // 256
#define O_NORMF 76032    // 1152
#define O_META  77184    // 1152
#define POOLSZ  78336
#define EPS     276      // epilogue row stride (floats), mult of 4

__device__ __forceinline__ ushort bf16_rne(float x) {
    uint u = __float_as_uint(x);
    return (ushort)((u + 0x7FFFu + ((u >> 16) & 1u)) >> 16);
}
__device__ __forceinline__ float bf16_to_f(ushort h) {
    return __uint_as_float(((uint)h) << 16);
}
__device__ __forceinline__ void gload_lds16(const void* g, void* l) {
    __builtin_amdgcn_global_load_lds(
        (const __attribute__((address_space(1))) uint*)g,
        (__attribute__((address_space(3))) uint*)l, 16, 0, 0);
}

// ---- prep: split cart2sph into bf16 hi/lo, chunk-major MFMA frag image ----
__global__ void prep_b(const float* __restrict__ c2s, ushort* __restrict__ wsHi,
                       ushort* __restrict__ wsLo) {
    int id = blockIdx.x * 256 + threadIdx.x;
    if (id >= KP * NCOLP) return;
    int k = id / NCOLP, col = id % NCOLP;
    float v = (k < NAOC && col < NAOS) ? c2s[k * NAOS + col] : 0.0f;
    ushort hi = bf16_rne(v);
    ushort lo = bf16_rne(v - bf16_to_f(hi));
    int off = (k >> 5) * BCH +
              (((col >> 4) * 4 + ((k & 31) >> 3)) * 16 + (col & 15)) * 8 + (k & 7);
    wsHi[off] = hi;
    wsLo[off] = lo;
}

template <bool USEWS>
__global__ __launch_bounds__(256, 2) void gto_mfma(
    const float* __restrict__ coords, const float* __restrict__ centers,
    const float* __restrict__ zetas, const float* __restrict__ coeffs,
    const float* __restrict__ norm, const float* __restrict__ c2s,
    const ushort* __restrict__ wsHi, const ushort* __restrict__ wsLo,
    float* __restrict__ out, int n)
{
    __shared__ __align__(16) char smem[POOLSZ];
    float*  sRad  = (float*)(smem + O_RAD);
    ushort* sBhi  = (ushort*)(smem + O_BHI);
    ushort* sBlo  = (ushort*)(smem + O_BLO);
    ushort* sAhi  = (ushort*)(smem + O_AHI);
    ushort* sAlo  = (ushort*)(smem + O_ALO);
    float*  sZeta = (float*)(smem + O_ZETA);
    float*  sCoef = (float*)(smem + O_COEF);
    float*  sCen  = (float*)(smem + O_CEN);
    float*  sCx   = (float*)(smem + O_CX);
    float*  sCy   = (float*)(smem + O_CY);
    float*  sCz   = (float*)(smem + O_CZ);
    float*  sNormF= (float*)(smem + O_NORMF);
    int*    sMeta = (int*)(smem + O_META);

    const int t = threadIdx.x, lane = t & 63, w = t >> 6;
    const int lr = lane & 15, lg4 = lane >> 4;
    const int P0 = blockIdx.x * MT;

    // ---- issue B chunk 0 loads early ----
    if (USEWS) {
        for (int r = w; r < 17; r += 4) {
            gload_lds16(wsHi + r * 512 + lane * 8, smem + O_BHI + r * 1024);
            gload_lds16(wsLo + r * 512 + lane * 8, smem + O_BLO + r * 1024);
        }
    }

    // ---- stage constants + metadata ----
    for (int i = t; i < NSH * NPRIM; i += 256) { sZeta[i] = zetas[i]; sCoef[i] = coeffs[i]; }
    for (int i = t; i < NATOM * 3; i += 256) sCen[i] = centers[i];
    for (int i = t; i < MT * 3; i += 256) {
        int gi = P0 * 3 + i;
        float v = (gi < 3 * n) ? coords[gi] : 0.0f;
        int p = i / 3, c = i - 3 * (i / 3);
        if (c == 0) sCx[p] = v; else if (c == 1) sCy[p] = v; else sCz[p] = v;
    }
    for (int k = t; k < KP; k += 256) {
        int shell = 0, atom = 0, s1 = 0, s2 = 0; float nf = 0.0f;
        if (k < 40) {
            atom = k >> 1; shell = 5 * atom + (k & 1); nf = norm[k];
        } else if (k < 160) {
            int i = k - 40; int ip = i / 3; int c = i - 3 * ip;
            atom = ip >> 1; shell = 5 * atom + 2 + (ip & 1); s1 = 1 + c; nf = norm[k];
        } else if (k < NAOC) {
            int i = k - 160; atom = i / 6; shell = 5 * atom + 4; int c = i - 6 * atom;
            if      (c == 0) { s1 = 1; s2 = 1; }
            else if (c == 1) { s1 = 1; s2 = 2; }
            else if (c == 2) { s1 = 1; s2 = 3; }
            else if (c == 3) { s1 = 2; s2 = 2; }
            else if (c == 4) { s1 = 2; s2 = 3; }
            else             { s1 = 3; s2 = 3; }
            nf = norm[k];
            if (c == 0 || c == 3 || c == 5) nf *= RSQRT3;
        }
        sMeta[k]  = shell | (atom << 7) | (s1 << 12) | (s2 << 14);
        sNormF[k] = nf;
    }
    __syncthreads();

    // ---- radial table rad[shell][point] ----
    #pragma unroll 1
    for (int it = 0; it < (NSH * MT) / 256; ++it) {
        int id = it * 256 + t;
        int s = id >> 6, p = id & 63;
        int a = s / 5;
        float dx = sCx[p] - sCen[3 * a];
        float dy = sCy[p] - sCen[3 * a + 1];
        float dz = sCz[p] - sCen[3 * a + 2];
        float r2 = dx * dx + dy * dy + dz * dz;
        float rad = 0.0f;
        #pragma unroll
        for (int pr = 0; pr < NPRIM; ++pr)
            rad += sCoef[s * NPRIM + pr] * __expf(-sZeta[s * NPRIM + pr] * r2);
        sRad[s * MT + p] = rad;
    }
    __syncthreads();

    // ---- A-build lambda: thread (p=lane, oct=w) -> 8 k's, 2x b128 write ----
    auto buildA = [&](int kb) {
        const int p = lane, oc = w;
        uint hp[4], lp[4];
        #pragma unroll
        for (int jp = 0; jp < 4; ++jp) {
            uint hw = 0, lw = 0;
            #pragma unroll
            for (int h = 0; h < 2; ++h) {
                int k = kb * 32 + oc * 8 + jp * 2 + h;
                int meta = sMeta[k];
                int s = meta & 127, a = (meta >> 7) & 31;
                int s1 = (meta >> 12) & 3, s2 = (meta >> 14) & 3;
                float dx = sCx[p] - sCen[3 * a];
                float dy = sCy[p] - sCen[3 * a + 1];
                float dz = sCz[p] - sCen[3 * a + 2];
                float m1 = (s1 == 0) ? 1.0f : ((s1 == 1) ? dx : ((s1 == 2) ? dy : dz));
                float m2 = (s2 == 0) ? 1.0f : ((s2 == 1) ? dx : ((s2 == 2) ? dy : dz));
                float v = sRad[s * MT + p] * (m1 * m2) * sNormF[k];
                ushort hi = bf16_rne(v);
                ushort lo = bf16_rne(v - bf16_to_f(hi));
                hw |= ((uint)hi) << (16 * h);
                lw |= ((uint)lo) << (16 * h);
            }
            hp[jp] = hw; lp[jp] = lw;
        }
        *(uint4v*)(sAhi + (oc * 64 + p) * 8) = (uint4v){hp[0], hp[1], hp[2], hp[3]};
        *(uint4v*)(sAlo + (oc * 64 + p) * 8) = (uint4v){lp[0], lp[1], lp[2], lp[3]};
    };

    buildA(0);
    __syncthreads();   // drains vmcnt: B0 in LDS, A0 in LDS

    f32x4 acc[5][4];
    #pragma unroll
    for (int i = 0; i < 5; ++i)
        #pragma unroll
        for (int m = 0; m < 4; ++m)
            acc[i][m] = (f32x4){0.0f, 0.0f, 0.0f, 0.0f};

    for (int kb = 0; kb < NKB; ++kb) {
        // ---- frag reads into registers ----
        short8 aH[4], aL[4], bH[5], bL[5];
        #pragma unroll
        for (int m = 0; m < 4; ++m) {
            aH[m] = *(const short8*)(sAhi + (lg4 * 64 + m * 16 + lr) * 8);
            aL[m] = *(const short8*)(sAlo + (lg4 * 64 + m * 16 + lr) * 8);
        }
        #pragma unroll
        for (int i = 0; i < 5; ++i) {
            if (i < 4 || w == 0) {
                int nt = (i == 4) ? 16 : (w * 4 + i);
                bH[i] = *(const short8*)(sBhi + (nt * 64 + lg4 * 16 + lr) * 8);
                bL[i] = *(const short8*)(sBlo + (nt * 64 + lg4 * 16 + lr) * 8);
            } else { bH[i] = (short8){0,0,0,0,0,0,0,0}; bL[i] = bH[i]; }
        }
        __syncthreads();   // all waves consumed sA/sB -> free for restage

        // ---- prefetch next chunk (loads overlap MFMAs below) ----
        if (kb + 1 < NKB) {
            if (USEWS) {
                const ushort* srcH = wsHi + (size_t)(kb + 1) * BCH;
                const ushort* srcL = wsLo + (size_t)(kb + 1) * BCH;
                for (int r = w; r < 17; r += 4) {
                    gload_lds16(srcH + r * 512 + lane * 8, smem + O_BHI + r * 1024);
                    gload_lds16(srcL + r * 512 + lane * 8, smem + O_BLO + r * 1024);
                }
            } else {
                for (int i2 = t; i2 < BCH; i2 += 256) {
                    int col = i2 % NCOLP, kl = i2 / NCOLP;
                    int k = (kb + 1) * 32 + kl;
                    float v = (k < NAOC && col < NAOS) ? c2s[k * NAOS + col] : 0.0f;
                    ushort hi = bf16_rne(v);
                    ushort lo = bf16_rne(v - bf16_to_f(hi));
                    int off = (((col >> 4) * 4 + (kl >> 3)) * 16 + (col & 15)) * 8 + (kl & 7);
                    sBhi[off] = hi; sBlo[off] = lo;
                }
            }
            buildA(kb + 1);
        }

        // ---- MFMAs (3-pass split-bf16) ----
        #pragma unroll
        for (int i = 0; i < 5; ++i) {
            if (i < 4 || w == 0) {
                #pragma unroll
                for (int m = 0; m < 4; ++m)
                    acc[i][m] = __builtin_amdgcn_mfma_f32_16x16x32_bf16(aH[m], bH[i], acc[i][m], 0, 0, 0);
                #pragma unroll
                for (int m = 0; m < 4; ++m)
                    acc[i][m] = __builtin_amdgcn_mfma_f32_16x16x32_bf16(aH[m], bL[i], acc[i][m], 0, 0, 0);
                #pragma unroll
                for (int m = 0; m < 4; ++m)
                    acc[i][m] = __builtin_amdgcn_mfma_f32_16x16x32_bf16(aL[m], bH[i], acc[i][m], 0, 0, 0);
            }
        }
        __syncthreads();   // vmcnt drained: next chunk staged
    }

    // ---- epilogue: acc -> LDS [64][EPS] -> coalesced row stores ----
    float* ep = (float*)smem;
    #pragma unroll
    for (int i = 0; i < 5; ++i) {
        if (i < 4 || w == 0) {
            int nt = (i == 4) ? 16 : (w * 4 + i);
            int col = nt * 16 + lr;
            #pragma unroll
            for (int m = 0; m < 4; ++m) {
                #pragma unroll
                for (int r = 0; r < 4; ++r)
                    ep[(m * 16 + lg4 * 4 + r) * EPS + col] = acc[i][m][r];
            }
        }
    }
    __syncthreads();

    // main: lane covers float4-col = lane (cols 0..255); rows strided by wave
    for (int row = w; row < MT; row += 4) {
        int P = P0 + row;
        if (P < n) {
            float4 v = *(const float4*)&ep[row * EPS + lane * 4];
            *(float4*)&out[(size_t)P * NAOS + lane * 4] = v;
        }
    }
    // tail: cols 256..259, one float4 per row, wave 0
    if (w == 0) {
        int P = P0 + lane;
        if (P < n) {
            float4 v = *(const float4*)&ep[lane * EPS + 256];
            *(float4*)&out[(size_t)P * NAOS + 256] = v;
        }
    }
}

extern "C" void kernel_launch(void* const* d_in, const int* in_sizes, int n_in,
                              void* d_out, int out_size, void* d_ws, size_t ws_size,
                              hipStream_t stream) {
    const float* coords  = (const float*)d_in[0];
    const float* centers = (const float*)d_in[1];
    const float* zetas   = (const float*)d_in[2];
    const float* coeffs  = (const float*)d_in[3];
    const float* norm    = (const float*)d_in[4];
    const float* c2s     = (const float*)d_in[5];
    float* out = (float*)d_out;
    int n = in_sizes[0] / 3;
    int grid = (n + MT - 1) / MT;

    const size_t WS_NEED = (size_t)2 * KP * NCOLP * sizeof(ushort);
    ushort* wsHi = (ushort*)d_ws;
    ushort* wsLo = wsHi + (size_t)KP * NCOLP;

    if (ws_size >= WS_NEED) {
        prep_b<<<(KP * NCOLP + 255) / 256, 256, 0, stream>>>(c2s, wsHi, wsLo);
        gto_mfma<true><<<grid, 256, 0, stream>>>(coords, centers, zetas, coeffs,
                                                 norm, c2s, wsHi, wsLo, out, n);
    } else {
        gto_mfma<false><<<grid, 256, 0, stream>>>(coords, centers, zetas, coeffs,
                                                  norm, c2s, nullptr, nullptr, out, n);
    }
}

// Round 5
// 112.399 us; speedup vs baseline: 6.8485x; 1.3480x over previous
//
#include <hip/hip_runtime.h>

typedef unsigned int uint;
typedef unsigned short ushort;
typedef __attribute__((ext_vector_type(8))) short short8;   // 8 bf16
typedef __attribute__((ext_vector_type(4))) float f32x4;
typedef __attribute__((ext_vector_type(2))) uint uint2v;

#define NSH   100
#define NPRIM 8
#define NAOC  280
#define NAOS  260
#define NATOM 20
#define KP    288
#define NKB   9
#define MT    32            // points per block
#define NCOLP 272
#define BCH   (32 * NCOLP)  // ushorts per chunk image (8704)
#define RSQRT3 0.57735026918962576f
#define EPS   276           // epilogue row stride (floats)

// LDS byte offsets (main phase pool; epilogue reuses from 0)
#define O_RAD   0        // 100*32*4 = 12800
#define O_AH    12800    // 2 bufs * 2048
#define O_AL    16896    // 2 bufs * 2048
#define O_ZETA  20992    // 3200
#define O_COEF  24192    // 3200
#define O_CEN   27392    // 240
#define O_CX    27648    // 128
#define O_CY    27776    // 128
#define O_CZ    27904    // 128
#define O_NORMF 28032    // KP*4 = 1152
#define O_META  29184    // KP*4 = 1152
#define POOLSZ  (MT * EPS * 4)   // 35328 (epilogue dominates)

__device__ __forceinline__ ushort bf16_rne(float x) {
    uint u = __float_as_uint(x);
    return (ushort)((u + 0x7FFFu + ((u >> 16) & 1u)) >> 16);
}
__device__ __forceinline__ float bf16_to_f(ushort h) {
    return __uint_as_float(((uint)h) << 16);
}

__device__ __forceinline__ int calc_meta(int k, float& anorm) {
    int shell = 0, atom = 0, s1 = 0, s2 = 0;
    anorm = 1.0f;
    if (k < 40) {
        atom = k >> 1; shell = 5 * atom + (k & 1);
    } else if (k < 160) {
        int i = k - 40; int ip = i / 3; int c = i - 3 * ip;
        atom = ip >> 1; shell = 5 * atom + 2 + (ip & 1); s1 = 1 + c;
    } else if (k < NAOC) {
        int i = k - 160; atom = i / 6; shell = 5 * atom + 4; int c = i - 6 * atom;
        if      (c == 0) { s1 = 1; s2 = 1; }
        else if (c == 1) { s1 = 1; s2 = 2; }
        else if (c == 2) { s1 = 1; s2 = 3; }
        else if (c == 3) { s1 = 2; s2 = 2; }
        else if (c == 4) { s1 = 2; s2 = 3; }
        else             { s1 = 3; s2 = 3; }
        if (c == 0 || c == 3 || c == 5) anorm = RSQRT3;
    }
    return shell | (atom << 7) | (s1 << 12) | (s2 << 14);
}

// ---- prep: split cart2sph to bf16 hi/lo frag image + meta/normf tables ----
__global__ void prep_b(const float* __restrict__ c2s, const float* __restrict__ norm,
                       ushort* __restrict__ wsHi, ushort* __restrict__ wsLo,
                       int* __restrict__ wsMeta, float* __restrict__ wsNorm) {
    if (blockIdx.x == 0) {
        // FIX (R4 bug): KP=288 > 256 threads -> strided loop, was `if (tid < KP)`
        for (int k = threadIdx.x; k < KP; k += 256) {
            float an;
            int m = calc_meta(k, an);
            wsMeta[k] = m;
            wsNorm[k] = (k < NAOC ? norm[k] : 0.0f) * an;
        }
    }
    int id = blockIdx.x * 256 + threadIdx.x;
    if (id >= KP * NCOLP) return;
    int k = id / NCOLP, col = id % NCOLP;
    float v = (k < NAOC && col < NAOS) ? c2s[k * NAOS + col] : 0.0f;
    ushort hi = bf16_rne(v);
    ushort lo = bf16_rne(v - bf16_to_f(hi));
    int off = (k >> 5) * BCH +
              (((col >> 4) * 4 + ((k & 31) >> 3)) * 16 + (col & 15)) * 8 + (k & 7);
    wsHi[off] = hi;
    wsLo[off] = lo;
}

template <bool USEWS>
__global__ __launch_bounds__(256, 4) void gto_mfma(
    const float* __restrict__ coords, const float* __restrict__ centers,
    const float* __restrict__ zetas, const float* __restrict__ coeffs,
    const float* __restrict__ norm, const float* __restrict__ c2s,
    const ushort* __restrict__ wsHi, const ushort* __restrict__ wsLo,
    const int* __restrict__ wsMeta, const float* __restrict__ wsNorm,
    float* __restrict__ out, int n)
{
    __shared__ __align__(16) char smem[POOLSZ];
    float*  sRad  = (float*)(smem + O_RAD);
    float*  sZeta = (float*)(smem + O_ZETA);
    float*  sCoef = (float*)(smem + O_COEF);
    float*  sCen  = (float*)(smem + O_CEN);
    float*  sCx   = (float*)(smem + O_CX);
    float*  sCy   = (float*)(smem + O_CY);
    float*  sCz   = (float*)(smem + O_CZ);
    float*  sNormF= (float*)(smem + O_NORMF);
    int*    sMeta = (int*)(smem + O_META);

    const int t = threadIdx.x, lane = t & 63, w = t >> 6;
    const int lr = lane & 15, lg4 = lane >> 4;
    const int P0 = blockIdx.x * MT;

    // ---- stage constants ----
    for (int i = t; i < NSH * NPRIM; i += 256) { sZeta[i] = zetas[i]; sCoef[i] = coeffs[i]; }
    if (t < NATOM * 3) sCen[t] = centers[t];
    if (t < MT * 3) {
        int gi = P0 * 3 + t;
        float v = (gi < 3 * n) ? coords[gi] : 0.0f;
        int p = t / 3, c = t - 3 * (t / 3);
        if (c == 0) sCx[p] = v; else if (c == 1) sCy[p] = v; else sCz[p] = v;
    }
    if (USEWS) {
        for (int i = t; i < KP; i += 256) { sMeta[i] = wsMeta[i]; sNormF[i] = wsNorm[i]; }
    } else {
        for (int k = t; k < KP; k += 256) {
            float an;
            sMeta[k] = calc_meta(k, an);
            sNormF[k] = (k < NAOC ? norm[k] : 0.0f) * an;
        }
    }
    __syncthreads();

    // ---- radial table rad[shell][point] ----
    #pragma unroll 1
    for (int it = 0; it < (NSH * MT + 255) / 256; ++it) {
        int id = it * 256 + t;
        if (id < NSH * MT) {
            int s = id >> 5, p = id & 31;
            int a = s / 5;
            float dx = sCx[p] - sCen[3 * a];
            float dy = sCy[p] - sCen[3 * a + 1];
            float dz = sCz[p] - sCen[3 * a + 2];
            float r2 = dx * dx + dy * dy + dz * dz;
            float rad = 0.0f;
            #pragma unroll
            for (int pr = 0; pr < NPRIM; ++pr)
                rad += sCoef[s * NPRIM + pr] * __expf(-sZeta[s * NPRIM + pr] * r2);
            sRad[s * MT + p] = rad;
        }
    }

    // ---- A-build: thread (oc=w, kh, p) -> 4 k's, b64 hi + b64 lo write ----
    const int kh = (t >> 5) & 1, pA = t & 31;
    auto buildA = [&](int kb2) {
        const float cxp = sCx[pA], cyp = sCy[pA], czp = sCz[pA];
        uint hw0 = 0, hw1 = 0, lw0 = 0, lw1 = 0;
        #pragma unroll
        for (int j = 0; j < 4; ++j) {
            int k = kb2 * 32 + w * 8 + kh * 4 + j;
            int meta = sMeta[k];
            int s = meta & 127, a = (meta >> 7) & 31;
            int s1 = (meta >> 12) & 3, s2 = (meta >> 14) & 3;
            float dx = cxp - sCen[3 * a];
            float dy = cyp - sCen[3 * a + 1];
            float dz = czp - sCen[3 * a + 2];
            float m1 = (s1 == 0) ? 1.0f : ((s1 == 1) ? dx : ((s1 == 2) ? dy : dz));
            float m2 = (s2 == 0) ? 1.0f : ((s2 == 1) ? dx : ((s2 == 2) ? dy : dz));
            float v = sRad[s * MT + pA] * (m1 * m2) * sNormF[k];
            ushort hi = bf16_rne(v);
            ushort lo = bf16_rne(v - bf16_to_f(hi));
            if (j < 2) { hw0 |= ((uint)hi) << (16 * j);      lw0 |= ((uint)lo) << (16 * j); }
            else       { hw1 |= ((uint)hi) << (16 * (j - 2)); lw1 |= ((uint)lo) << (16 * (j - 2)); }
        }
        int boff = (kb2 & 1) * 2048 + ((w * 32 + pA) * 8 + kh * 4) * 2;
        *(uint2v*)(smem + O_AH + boff) = (uint2v){hw0, hw1};
        *(uint2v*)(smem + O_AL + boff) = (uint2v){lw0, lw1};
    };

    __syncthreads();   // sRad ready
    buildA(0);

    f32x4 acc[5][2];
    #pragma unroll
    for (int i = 0; i < 5; ++i)
        #pragma unroll
        for (int mt = 0; mt < 2; ++mt)
            acc[i][mt] = (f32x4){0.0f, 0.0f, 0.0f, 0.0f};

    for (int kb = 0; kb < NKB; ++kb) {
        __syncthreads();   // A(kb) writes visible; lgkm-only (no vmem drain needed)

        // A frags from buf kb&1
        short8 aH[2], aL[2];
        #pragma unroll
        for (int mt = 0; mt < 2; ++mt) {
            int off = (kb & 1) * 2048 + (lg4 * 32 + mt * 16 + lr) * 16;
            aH[mt] = *(const short8*)(smem + O_AH + off);
            aL[mt] = *(const short8*)(smem + O_AL + off);
        }

        // build next chunk's A into the other buffer (fills MFMA/vmem shadows)
        if (kb + 1 < NKB) buildA(kb + 1);

        // MFMAs with B direct from global (L2-resident ws)
        #pragma unroll
        for (int i = 0; i < 5; ++i) {
            if (i < 4 || w == 0) {
                int nt = (i == 4) ? 16 : (w * 4 + i);
                short8 bh, bl;
                if (USEWS) {
                    bh = *(const short8*)(wsHi + (size_t)kb * BCH + (nt * 64 + lane) * 8);
                    bl = *(const short8*)(wsLo + (size_t)kb * BCH + (nt * 64 + lane) * 8);
                } else {
                    #pragma unroll
                    for (int j = 0; j < 8; ++j) {
                        int k = kb * 32 + lg4 * 8 + j;
                        int col = nt * 16 + lr;
                        float v = (k < NAOC && col < NAOS) ? c2s[k * NAOS + col] : 0.0f;
                        ushort hi = bf16_rne(v);
                        bh[j] = (short)hi;
                        bl[j] = (short)bf16_rne(v - bf16_to_f(hi));
                    }
                }
                #pragma unroll
                for (int mt = 0; mt < 2; ++mt)
                    acc[i][mt] = __builtin_amdgcn_mfma_f32_16x16x32_bf16(aH[mt], bh, acc[i][mt], 0, 0, 0);
                #pragma unroll
                for (int mt = 0; mt < 2; ++mt)
                    acc[i][mt] = __builtin_amdgcn_mfma_f32_16x16x32_bf16(aH[mt], bl, acc[i][mt], 0, 0, 0);
                #pragma unroll
                for (int mt = 0; mt < 2; ++mt)
                    acc[i][mt] = __builtin_amdgcn_mfma_f32_16x16x32_bf16(aL[mt], bh, acc[i][mt], 0, 0, 0);
            }
        }
    }

    // ---- epilogue: acc -> LDS [32][EPS] -> coalesced row stores ----
    __syncthreads();
    float* ep = (float*)smem;
    #pragma unroll
    for (int i = 0; i < 5; ++i) {
        if (i < 4 || w == 0) {
            int nt = (i == 4) ? 16 : (w * 4 + i);
            int col = nt * 16 + lr;
            #pragma unroll
            for (int mt = 0; mt < 2; ++mt)
                #pragma unroll
                for (int r = 0; r < 4; ++r)
                    ep[(mt * 16 + lg4 * 4 + r) * EPS + col] = acc[i][mt][r];
        }
    }
    __syncthreads();

    for (int row = w; row < MT; row += 4) {
        int P = P0 + row;
        if (P < n)
            *(float4*)&out[(size_t)P * NAOS + lane * 4] = *(const float4*)&ep[row * EPS + lane * 4];
    }
    if (w == 1 && lane < MT) {
        int P = P0 + lane;
        if (P < n)
            *(float4*)&out[(size_t)P * NAOS + 256] = *(const float4*)&ep[lane * EPS + 256];
    }
}

extern "C" void kernel_launch(void* const* d_in, const int* in_sizes, int n_in,
                              void* d_out, int out_size, void* d_ws, size_t ws_size,
                              hipStream_t stream) {
    const float* coords  = (const float*)d_in[0];
    const float* centers = (const float*)d_in[1];
    const float* zetas   = (const float*)d_in[2];
    const float* coeffs  = (const float*)d_in[3];
    const float* norm    = (const float*)d_in[4];
    const float* c2s     = (const float*)d_in[5];
    float* out = (float*)d_out;
    int n = in_sizes[0] / 3;
    int grid = (n + MT - 1) / MT;

    ushort* wsHi = (ushort*)d_ws;
    ushort* wsLo = wsHi + (size_t)KP * NCOLP;
    int*    wsMeta = (int*)(wsLo + (size_t)KP * NCOLP);
    float*  wsNorm = (float*)(wsMeta + KP);
    const size_t WS_NEED = (size_t)2 * KP * NCOLP * sizeof(ushort) + KP * 8;

    if (ws_size >= WS_NEED) {
        prep_b<<<(KP * NCOLP + 255) / 256, 256, 0, stream>>>(c2s, norm, wsHi, wsLo, wsMeta, wsNorm);
        gto_mfma<true><<<grid, 256, 0, stream>>>(coords, centers, zetas, coeffs, norm, c2s,
                                                 wsHi, wsLo, wsMeta, wsNorm, out, n);
    } else {
        gto_mfma<false><<<grid, 256, 0, stream>>>(coords, centers, zetas, coeffs, norm, c2s,
                                                  nullptr, nullptr, nullptr, nullptr, out, n);
    }
}